// Round 5
// baseline (14218.390 us; speedup 1.0000x reference)
//
#include <hip/hip_runtime.h>
#include <math.h>

// GRU rollout. Hidden-dim split across wgs, weights LDS-resident (float4
// broadcasts), h stored float4-TRANSPOSED hq[kq][row] for coalesced loads,
// 2 batch rows per thread to amortize LDS broadcasts. Relaunch per step.
//
// Fusions (exact fp32 algebra):
//   p_{s-1} = h_{s-1} @ Wp^T + bp   =>   x_s = [p_{s-1}, lat, lon]
//   gi = h_{s-1} @ Wf^T + const,  Wf = Wih[:,:256] @ Wp  (precomputed once)
//   r,z rows combined: Wc_rz = Wf_rz + Whh_rz ; n rows kept separate.

#define B_SZ   2048
#define LAT    256
#define HID    512
#define NTHR   256
#define NWG    512          // 128 unit-groups x 4 row-groups
#define HBUF   (B_SZ * HID) // one h buffer in floats (= 128*2048 float4)
#define HQ_N   (128 * 2048) // one h buffer in float4s

__device__ __forceinline__ float sigm(float x) {
    return 1.0f / (1.0f + __expf(-x));
}
__device__ __forceinline__ float tanh_f(float x) {
    float e = __expf(-2.0f * fabsf(x));
    float t = (1.0f - e) / (1.0f + e);
    return copysignf(t, x);
}

// ---------------- precompute: Wc[512 units][4][512] ----------------
// rows per unit u: [0]=Wf_r+Whh_r, [1]=Wf_z+Whh_z, [2]=Wf_n, [3]=Whh_n
__global__ __launch_bounds__(512) void k_wf(
    const float* __restrict__ W_ih, const float* __restrict__ W_hh,
    const float* __restrict__ W_pr, float* __restrict__ Wc)
{
    const int u = blockIdx.x;     // hidden unit
    const int k = threadIdx.x;    // output column
    __shared__ float wih_s[3][256];
    for (int i = threadIdx.x; i < 3 * 256; i += 512) {
        int j = i >> 8, o = i & 255;
        wih_s[j][o] = W_ih[(size_t)(j * HID + u) * 258 + o];
    }
    __syncthreads();
    float fr = 0.f, fz = 0.f, fn = 0.f;
    for (int o = 0; o < 256; ++o) {
        float wp = W_pr[(size_t)o * HID + k];
        fr = fmaf(wih_s[0][o], wp, fr);
        fz = fmaf(wih_s[1][o], wp, fz);
        fn = fmaf(wih_s[2][o], wp, fn);
    }
    float* dst = Wc + (size_t)u * 4 * HID;
    dst[0 * HID + k] = fr + W_hh[(size_t)u * HID + k];
    dst[1 * HID + k] = fz + W_hh[(size_t)(HID + u) * HID + k];
    dst[2 * HID + k] = fn;
    dst[3 * HID + k] = W_hh[(size_t)(2 * HID + u) * HID + k];
}

// ---------------- precompute: Bias[512][12] ----------------
// [0]Br(+bhh) [1]c1r [2]c2r [3]Bz(+bhh) [4]c1z [5]c2z
// [6]Bn_i     [7]c1n [8]c2n [9]bhh_n [10]bhh_r [11]bhh_z
__global__ __launch_bounds__(64) void k_bias(
    const float* __restrict__ W_ih, const float* __restrict__ b_ih,
    const float* __restrict__ b_hh, const float* __restrict__ b_pr,
    float* __restrict__ Bias)
{
    const int u = blockIdx.x;
    const int t = threadIdx.x;
    float dr = 0.f, dz = 0.f, dn = 0.f;
    for (int o = t; o < 256; o += 64) {
        float bo = b_pr[o];
        dr = fmaf(bo, W_ih[(size_t)u * 258 + o], dr);
        dz = fmaf(bo, W_ih[(size_t)(HID + u) * 258 + o], dz);
        dn = fmaf(bo, W_ih[(size_t)(2 * HID + u) * 258 + o], dn);
    }
    #pragma unroll
    for (int off = 32; off > 0; off >>= 1) {
        dr += __shfl_down(dr, off);
        dz += __shfl_down(dz, off);
        dn += __shfl_down(dn, off);
    }
    if (t == 0) {
        float* b = Bias + u * 12;
        b[0]  = b_ih[u] + b_hh[u] + dr;
        b[1]  = W_ih[(size_t)u * 258 + 256];
        b[2]  = W_ih[(size_t)u * 258 + 257];
        b[3]  = b_ih[HID + u] + b_hh[HID + u] + dz;
        b[4]  = W_ih[(size_t)(HID + u) * 258 + 256];
        b[5]  = W_ih[(size_t)(HID + u) * 258 + 257];
        b[6]  = b_ih[2 * HID + u] + dn;
        b[7]  = W_ih[(size_t)(2 * HID + u) * 258 + 256];
        b[8]  = W_ih[(size_t)(2 * HID + u) * 258 + 257];
        b[9]  = b_hh[2 * HID + u];
        b[10] = b_hh[u];
        b[11] = b_hh[HID + u];
    }
}

// ---------------- precompute: gi1_T[1536][2048] = x1 @ Wih^T + b_ih; out[0]=p0
__global__ __launch_bounds__(512) void k_gi1(
    const float* __restrict__ p0, const float* __restrict__ latv,
    const float* __restrict__ lonv, const float* __restrict__ W_ih,
    const float* __restrict__ b_ih, float* __restrict__ gi1T,
    float* __restrict__ out)
{
    const int rb = blockIdx.x;            // 256 blocks x 8 rows
    const int t  = threadIdx.x;
    __shared__ float p0s[8][256];
    __shared__ float lat_s[8], lon_s[8];
    for (int i = t; i < 8 * 256; i += 512) {
        int r = i >> 8, o = i & 255;
        float v = p0[(size_t)(rb * 8 + r) * LAT + o];
        p0s[r][o] = v;
        out[(size_t)(rb * 8 + r) * LAT + o] = v;   // out[0] = p0
    }
    if (t < 8) { lat_s[t] = latv[rb * 8 + t]; lon_s[t] = lonv[rb * 8 + t]; }
    __syncthreads();

    for (int gg = 0; gg < 3; ++gg) {
        const int grow = t + gg * 512;
        const float* wr = W_ih + (size_t)grow * 258;
        float acc[8];
        float bi = b_ih[grow];
        #pragma unroll
        for (int r = 0; r < 8; ++r) acc[r] = bi;
        for (int o = 0; o < 256; ++o) {
            float wv = wr[o];
            #pragma unroll
            for (int r = 0; r < 8; ++r) acc[r] = fmaf(wv, p0s[r][o], acc[r]);
        }
        float c1 = wr[256], c2 = wr[257];
        #pragma unroll
        for (int r = 0; r < 8; ++r) {
            acc[r] = fmaf(lat_s[r], c1, acc[r]);
            acc[r] = fmaf(lon_s[r], c2, acc[r]);
            gi1T[(size_t)grow * B_SZ + rb * 8 + r] = acc[r];
        }
    }
}

// ---- gate nonlinearity for 4 units of one row ----
__device__ __forceinline__ void gates4(const float* a, const float bias_s[4][12],
                                       float lt, float ln, const float* hold,
                                       float* hn)
{
    #pragma unroll
    for (int u = 0; u < 4; ++u) {
        float pre_r = a[u * 4 + 0] + bias_s[u][0] + lt * bias_s[u][1] + ln * bias_s[u][2];
        float pre_z = a[u * 4 + 1] + bias_s[u][3] + lt * bias_s[u][4] + ln * bias_s[u][5];
        float i_n   = a[u * 4 + 2] + bias_s[u][6] + lt * bias_s[u][7] + ln * bias_s[u][8];
        float h_n   = a[u * 4 + 3] + bias_s[u][9];
        float r = sigm(pre_r);
        float z = sigm(pre_z);
        float n = tanh_f(fmaf(r, h_n, i_n));
        hn[u] = n + z * (hold[u] - n);
    }
}

// ---------------- main step kernel ----------------
// hq layout: float4 hq[buf][kq][row], kq = k/4 (0..127), row 0..2047.
__global__ __launch_bounds__(NTHR, 2) void k_step(
    const float* __restrict__ Wc, const float* __restrict__ Bias,
    const float* __restrict__ W_pr, const float* __restrict__ b_pr,
    const float* __restrict__ gi1T, const float* __restrict__ latv,
    const float* __restrict__ lonv, float4* __restrict__ hq,
    float* __restrict__ out, int s, int ns)
{
    const int gid  = blockIdx.x;
    const int w    = gid >> 2;          // unit-group 0..127 (units u0..u0+3)
    const int rg   = gid & 3;           // row-group 0..3
    const int u0   = w * 4;
    const int o0   = w * 2;             // 2 proj columns
    const int t    = threadIdx.x;
    const int rowA = rg * 512 + t;
    const int rowB = rowA + 256;

    __shared__ float wc[4][4][HID];     // 32 KB
    __shared__ float wp_s[2][HID];      // 4 KB
    __shared__ float bias_s[4][12];

    {
        const float4* src = (const float4*)(Wc + (size_t)u0 * 4 * HID);
        float4* dst = (float4*)wc;
        #pragma unroll
        for (int i = 0; i < 8; ++i) dst[t + i * NTHR] = src[t + i * NTHR];
        ((float4*)wp_s)[t] = ((const float4*)(W_pr + (size_t)o0 * HID))[t];
        if (t < 48) ((float*)bias_s)[t] = Bias[u0 * 12 + t];
    }
    __syncthreads();

    const float4* __restrict__ hcur = hq + (size_t)((s - 1) & 1) * HQ_N;
    float4*       __restrict__ hnxt = hq + (size_t)(s & 1) * HQ_N;

    float aA[16], aB[16];
    float pA0 = 0.f, pA1 = 0.f, pB0 = 0.f, pB1 = 0.f;
    #pragma unroll
    for (int i = 0; i < 16; ++i) { aA[i] = 0.f; aB[i] = 0.f; }

    if (s >= 2) {
        float4 hA = hcur[rowA], hB = hcur[rowB];
        #pragma unroll 2
        for (int kq = 0; kq < 128; ++kq) {
            // prefetch next kq (kq=128 overreads into next ws region: allocated, unused)
            float4 nA = hcur[(size_t)(kq + 1) * B_SZ + rowA];
            float4 nB = hcur[(size_t)(kq + 1) * B_SZ + rowB];
            #pragma unroll
            for (int u = 0; u < 4; ++u) {
                #pragma unroll
                for (int g2 = 0; g2 < 4; ++g2) {
                    float4 wv = *(const float4*)&wc[u][g2][4 * kq];  // b128 broadcast
                    const int i = u * 4 + g2;
                    aA[i] = fmaf(wv.x, hA.x, aA[i]); aA[i] = fmaf(wv.y, hA.y, aA[i]);
                    aA[i] = fmaf(wv.z, hA.z, aA[i]); aA[i] = fmaf(wv.w, hA.w, aA[i]);
                    aB[i] = fmaf(wv.x, hB.x, aB[i]); aB[i] = fmaf(wv.y, hB.y, aB[i]);
                    aB[i] = fmaf(wv.z, hB.z, aB[i]); aB[i] = fmaf(wv.w, hB.w, aB[i]);
                }
            }
            {
                float4 wv = *(const float4*)&wp_s[0][4 * kq];
                pA0 = fmaf(wv.x, hA.x, pA0); pA0 = fmaf(wv.y, hA.y, pA0);
                pA0 = fmaf(wv.z, hA.z, pA0); pA0 = fmaf(wv.w, hA.w, pA0);
                pB0 = fmaf(wv.x, hB.x, pB0); pB0 = fmaf(wv.y, hB.y, pB0);
                pB0 = fmaf(wv.z, hB.z, pB0); pB0 = fmaf(wv.w, hB.w, pB0);
                wv = *(const float4*)&wp_s[1][4 * kq];
                pA1 = fmaf(wv.x, hA.x, pA1); pA1 = fmaf(wv.y, hA.y, pA1);
                pA1 = fmaf(wv.z, hA.z, pA1); pA1 = fmaf(wv.w, hA.w, pA1);
                pB1 = fmaf(wv.x, hB.x, pB1); pB1 = fmaf(wv.y, hB.y, pB1);
                pB1 = fmaf(wv.z, hB.z, pB1); pB1 = fmaf(wv.w, hB.w, pB1);
            }
            hA = nA; hB = nB;
        }
    }

    // ---- gates -> h_s (transposed float4 store) ----
    if (s <= ns) {
        float hnA[4], hnB[4];
        if (s == 1) {
            #pragma unroll
            for (int u = 0; u < 4; ++u) {
                // rowA
                float r = sigm(gi1T[(size_t)(u0 + u) * B_SZ + rowA] + bias_s[u][10]);
                float z = sigm(gi1T[(size_t)(HID + u0 + u) * B_SZ + rowA] + bias_s[u][11]);
                float n = tanh_f(fmaf(r, bias_s[u][9],
                                      gi1T[(size_t)(2 * HID + u0 + u) * B_SZ + rowA]));
                hnA[u] = n - z * n;    // hold = 0
                // rowB
                r = sigm(gi1T[(size_t)(u0 + u) * B_SZ + rowB] + bias_s[u][10]);
                z = sigm(gi1T[(size_t)(HID + u0 + u) * B_SZ + rowB] + bias_s[u][11]);
                n = tanh_f(fmaf(r, bias_s[u][9],
                                gi1T[(size_t)(2 * HID + u0 + u) * B_SZ + rowB]));
                hnB[u] = n - z * n;
            }
        } else {
            float4 hoA = hcur[(size_t)w * B_SZ + rowA];
            float4 hoB = hcur[(size_t)w * B_SZ + rowB];
            float holdA[4] = { hoA.x, hoA.y, hoA.z, hoA.w };
            float holdB[4] = { hoB.x, hoB.y, hoB.z, hoB.w };
            gates4(aA, bias_s, latv[rowA], lonv[rowA], holdA, hnA);
            gates4(aB, bias_s, latv[rowB], lonv[rowB], holdB, hnB);
        }
        hnxt[(size_t)w * B_SZ + rowA] = make_float4(hnA[0], hnA[1], hnA[2], hnA[3]);
        hnxt[(size_t)w * B_SZ + rowB] = make_float4(hnB[0], hnB[1], hnB[2], hnB[3]);
    }

    // ---- output p_{s-1} ----
    if (s >= 2) {
        const float bp0 = b_pr[o0], bp1 = b_pr[o0 + 1];
        float* oA = out + (size_t)(s - 1) * B_SZ * LAT + (size_t)rowA * LAT;
        float* oB = out + (size_t)(s - 1) * B_SZ * LAT + (size_t)rowB * LAT;
        oA[o0] = pA0 + bp0; oA[o0 + 1] = pA1 + bp1;
        oB[o0] = pB0 + bp0; oB[o0 + 1] = pB1 + bp1;
    }
}

extern "C" void kernel_launch(void* const* d_in, const int* in_sizes, int n_in,
                              void* d_out, int out_size, void* d_ws, size_t ws_size,
                              hipStream_t stream)
{
    const float* p0   = (const float*)d_in[0];
    const float* latv = (const float*)d_in[1];
    const float* lonv = (const float*)d_in[2];
    const float* W_ih = (const float*)d_in[3];
    const float* W_hh = (const float*)d_in[4];
    const float* b_ih = (const float*)d_in[5];
    const float* b_hh = (const float*)d_in[6];
    const float* W_pr = (const float*)d_in[7];
    const float* b_pr = (const float*)d_in[8];
    float* out = (float*)d_out;

    const int NS = out_size / (B_SZ * LAT) - 1;   // 100

    // workspace layout (floats)
    float* base = (float*)d_ws;
    float4* hq  = (float4*)base;                  // 2 * 128*2048 float4 = 2*HBUF floats
    float* gi1T = base + 2 * HBUF;                // 1536 * 2048
    float* Wc   = gi1T + 3 * HID * B_SZ;          // 512 * 4 * 512
    float* Bias = Wc + (size_t)HID * 4 * HID;     // 512 * 12

    hipLaunchKernelGGL(k_wf,   dim3(HID), dim3(512), 0, stream, W_ih, W_hh, W_pr, Wc);
    hipLaunchKernelGGL(k_bias, dim3(HID), dim3(64),  0, stream, W_ih, b_ih, b_hh, b_pr, Bias);
    hipLaunchKernelGGL(k_gi1,  dim3(256), dim3(512), 0, stream, p0, latv, lonv, W_ih, b_ih, gi1T, out);

    for (int s = 1; s <= NS + 1; ++s) {
        hipLaunchKernelGGL(k_step, dim3(NWG), dim3(NTHR), 0, stream,
                           Wc, Bias, W_pr, b_pr, gi1T, latv, lonv, hq, out, s, NS);
    }
}

// Round 6
// 7488.055 us; speedup vs baseline: 1.8988x; 1.8988x over previous
//
#include <hip/hip_runtime.h>
#include <math.h>

// GRU rollout via MFMA (bf16 hi/lo split, 3-pass => ~fp32 precision).
// Per step s: G[2048 x 2304] = h_{s-1}[2048x512] @ Wcat^T, where Wcat rows:
//   n < 2048: unit u=n>>2, gate g=n&3: [Wf_r+Whh_r, Wf_z+Whh_z, Wf_n, Whh_n]
//   n >= 2048: W_proj rows  (proj output p_{s-1} -> out[s-1])
// Gate epilogue (fused): h_s = (1-z)n + z h_{s-1}, stored as bf16 hi+lo.
// Step 1 handled via gi1 = x1 @ Wih^T + b_ih precompute (h0 = 0).

#define B_SZ 2048
#define LAT  256
#define HID  512
#define NROW 2304
#define HN   (B_SZ * HID)

typedef unsigned short u16;
typedef __attribute__((ext_vector_type(4))) short s16x4;
typedef __attribute__((ext_vector_type(8))) short s16x8;
typedef __attribute__((ext_vector_type(4))) float f32x4;

#define HALF(v, h) __builtin_shufflevector(v, v, (h)*4+0, (h)*4+1, (h)*4+2, (h)*4+3)

__device__ __forceinline__ float sigm(float x) { return 1.0f / (1.0f + __expf(-x)); }
__device__ __forceinline__ float tanh_f(float x) {
    float e = __expf(-2.0f * fabsf(x));
    float t = (1.0f - e) / (1.0f + e);
    return copysignf(t, x);
}
__device__ __forceinline__ u16 f2bf(float x) {
    unsigned u = __float_as_uint(x);
    return (u16)((u + 0x7FFFu + ((u >> 16) & 1u)) >> 16);
}
__device__ __forceinline__ float bf2f(u16 h) { return __uint_as_float((unsigned)h << 16); }

__device__ __forceinline__ f32x4 mfma16(s16x4 a, s16x4 b, f32x4 c) {
    return __builtin_amdgcn_mfma_f32_16x16x16bf16_1k(a, b, c, 0, 0, 0);
}

// ---------------- Bias[512][12] ----------------
// [0]Br [1]c1r [2]c2r [3]Bz [4]c1z [5]c2z [6]Bn_i [7]c1n [8]c2n [9]bhh_n [10]bhh_r [11]bhh_z
__global__ __launch_bounds__(64) void k_bias(
    const float* __restrict__ W_ih, const float* __restrict__ b_ih,
    const float* __restrict__ b_hh, const float* __restrict__ b_pr,
    float* __restrict__ Bias)
{
    const int u = blockIdx.x;
    const int t = threadIdx.x;
    float dr = 0.f, dz = 0.f, dn = 0.f;
    for (int o = t; o < 256; o += 64) {
        float bo = b_pr[o];
        dr = fmaf(bo, W_ih[(size_t)u * 258 + o], dr);
        dz = fmaf(bo, W_ih[(size_t)(HID + u) * 258 + o], dz);
        dn = fmaf(bo, W_ih[(size_t)(2 * HID + u) * 258 + o], dn);
    }
    #pragma unroll
    for (int off = 32; off > 0; off >>= 1) {
        dr += __shfl_down(dr, off);
        dz += __shfl_down(dz, off);
        dn += __shfl_down(dn, off);
    }
    if (t == 0) {
        float* b = Bias + u * 12;
        b[0]  = b_ih[u] + b_hh[u] + dr;
        b[1]  = W_ih[(size_t)u * 258 + 256];
        b[2]  = W_ih[(size_t)u * 258 + 257];
        b[3]  = b_ih[HID + u] + b_hh[HID + u] + dz;
        b[4]  = W_ih[(size_t)(HID + u) * 258 + 256];
        b[5]  = W_ih[(size_t)(HID + u) * 258 + 257];
        b[6]  = b_ih[2 * HID + u] + dn;
        b[7]  = W_ih[(size_t)(2 * HID + u) * 258 + 256];
        b[8]  = W_ih[(size_t)(2 * HID + u) * 258 + 257];
        b[9]  = b_hh[2 * HID + u];
        b[10] = b_hh[u];
        b[11] = b_hh[HID + u];
    }
}

// ---------------- gi1_T[1536][2048] = x1 @ Wih^T + b_ih; out[0] = p0 ----------------
__global__ __launch_bounds__(512) void k_gi1(
    const float* __restrict__ p0, const float* __restrict__ latv,
    const float* __restrict__ lonv, const float* __restrict__ W_ih,
    const float* __restrict__ b_ih, float* __restrict__ gi1T,
    float* __restrict__ out)
{
    const int rb = blockIdx.x;
    const int t  = threadIdx.x;
    __shared__ float p0s[8][256];
    __shared__ float lat_s[8], lon_s[8];
    for (int i = t; i < 8 * 256; i += 512) {
        int r = i >> 8, o = i & 255;
        float v = p0[(size_t)(rb * 8 + r) * LAT + o];
        p0s[r][o] = v;
        out[(size_t)(rb * 8 + r) * LAT + o] = v;
    }
    if (t < 8) { lat_s[t] = latv[rb * 8 + t]; lon_s[t] = lonv[rb * 8 + t]; }
    __syncthreads();

    for (int gg = 0; gg < 3; ++gg) {
        const int grow = t + gg * 512;
        const float* wr = W_ih + (size_t)grow * 258;
        float acc[8];
        float bi = b_ih[grow];
        #pragma unroll
        for (int r = 0; r < 8; ++r) acc[r] = bi;
        for (int o = 0; o < 256; ++o) {
            float wv = wr[o];
            #pragma unroll
            for (int r = 0; r < 8; ++r) acc[r] = fmaf(wv, p0s[r][o], acc[r]);
        }
        float c1 = wr[256], c2 = wr[257];
        #pragma unroll
        for (int r = 0; r < 8; ++r) {
            acc[r] = fmaf(lat_s[r], c1, acc[r]);
            acc[r] = fmaf(lon_s[r], c2, acc[r]);
            gi1T[(size_t)grow * B_SZ + rb * 8 + r] = acc[r];
        }
    }
}

// ---------------- h_1 from gi1 (h_0 = 0), stored bf16 hi/lo into buf 1 ----------------
__global__ __launch_bounds__(256) void k_h1(
    const float* __restrict__ gi1T, const float* __restrict__ Bias,
    u16* __restrict__ Hhi, u16* __restrict__ Hlo)
{
    const int idx = blockIdx.x * 256 + threadIdx.x;   // 2048*512
    const int row = idx & (B_SZ - 1);
    const int u   = idx >> 11;
    const float* bb = Bias + (size_t)u * 12;
    float r = sigm(gi1T[(size_t)u * B_SZ + row] + bb[10]);
    float z = sigm(gi1T[(size_t)(HID + u) * B_SZ + row] + bb[11]);
    float n = tanh_f(fmaf(r, bb[9], gi1T[(size_t)(2 * HID + u) * B_SZ + row]));
    float h = n - z * n;
    u16 hi = f2bf(h);
    Hhi[HN + (size_t)row * HID + u] = hi;
    Hlo[HN + (size_t)row * HID + u] = f2bf(h - bf2f(hi));
}

// ---------------- Wcat (2304 x 512) fused + split to bf16 hi/lo ----------------
__global__ __launch_bounds__(512) void k_wsplit(
    const float* __restrict__ W_ih, const float* __restrict__ W_hh,
    const float* __restrict__ W_pr, u16* __restrict__ Whi, u16* __restrict__ Wlo)
{
    const int n = blockIdx.x;
    const int k = threadIdx.x;
    const int u = n >> 2, g = n & 3;
    __shared__ float wr[256];
    if (n < 2048 && g != 3 && k < 256)
        wr[k] = W_ih[(size_t)(g * HID + u) * 258 + k];
    __syncthreads();

    float w;
    if (n >= 2048) {
        w = W_pr[(size_t)(n - 2048) * HID + k];
    } else if (g == 3) {
        w = W_hh[(size_t)(2 * HID + u) * HID + k];
    } else {
        float acc = 0.f;
        for (int o = 0; o < 256; ++o)
            acc = fmaf(wr[o], W_pr[(size_t)o * HID + k], acc);
        if (g == 0)      acc += W_hh[(size_t)u * HID + k];
        else if (g == 1) acc += W_hh[(size_t)(HID + u) * HID + k];
        w = acc;   // g==2: Wf_n only
    }
    u16 hi = f2bf(w);
    Whi[(size_t)n * HID + k] = hi;
    Wlo[(size_t)n * HID + k] = f2bf(w - bf2f(hi));
}

// ---------------- main MFMA step ----------------
// wg = 256 thr = 4 waves (2M x 2N of 32x32), wg tile 64x64, K = 512.
__global__ __launch_bounds__(256) void k_gemm(
    u16* __restrict__ Hhi, u16* __restrict__ Hlo,
    const u16* __restrict__ Whi, const u16* __restrict__ Wlo,
    const float* __restrict__ Bias, const float* __restrict__ b_pr,
    const float* __restrict__ latv, const float* __restrict__ lonv,
    float* __restrict__ out, int s, int ns, int ntb, int ntc)
{
    const int bid  = blockIdx.x;
    const int nt   = ntb + bid % ntc;
    const int mt   = bid / ntc;
    const int m0   = mt * 64, n0 = nt * 64;
    const int t    = threadIdx.x;
    const int lane = t & 63, wave = t >> 6;
    const int wm   = wave >> 1, wn = wave & 1;
    const int q    = lane >> 4, c = lane & 15;

    const u16* __restrict__ Hh = Hhi + (size_t)((s - 1) & 1) * HN;
    const u16* __restrict__ Hl = Hlo + (size_t)((s - 1) & 1) * HN;

    const size_t a0 = (size_t)(m0 + wm * 32 + c) * HID + 8 * q;
    const size_t a1 = a0 + 16 * HID;
    const size_t b0 = (size_t)(n0 + wn * 32 + c) * HID + 8 * q;
    const size_t b1 = b0 + 16 * HID;

    f32x4 acc00 = {0.f, 0.f, 0.f, 0.f}, acc01 = acc00, acc10 = acc00, acc11 = acc00;

    #pragma unroll 2
    for (int sc = 0; sc < 16; ++sc) {
        const int ko = sc * 32;           // shorts; k = 32*sc + 8*q + elem
        s16x8 ah0 = *(const s16x8*)(Hh  + a0 + ko);
        s16x8 ah1 = *(const s16x8*)(Hh  + a1 + ko);
        s16x8 al0 = *(const s16x8*)(Hl  + a0 + ko);
        s16x8 al1 = *(const s16x8*)(Hl  + a1 + ko);
        s16x8 bh0 = *(const s16x8*)(Whi + b0 + ko);
        s16x8 bh1 = *(const s16x8*)(Whi + b1 + ko);
        s16x8 bl0 = *(const s16x8*)(Wlo + b0 + ko);
        s16x8 bl1 = *(const s16x8*)(Wlo + b1 + ko);
        // half 0
        {
            s16x4 A0 = HALF(ah0, 0), A1 = HALF(ah1, 0), B0 = HALF(bh0, 0), B1 = HALF(bh1, 0);
            s16x4 L0 = HALF(al0, 0), L1 = HALF(al1, 0), M0 = HALF(bl0, 0), M1 = HALF(bl1, 0);
            acc00 = mfma16(A0, B0, acc00); acc01 = mfma16(A0, B1, acc01);
            acc10 = mfma16(A1, B0, acc10); acc11 = mfma16(A1, B1, acc11);
            acc00 = mfma16(L0, B0, acc00); acc01 = mfma16(L0, B1, acc01);
            acc10 = mfma16(L1, B0, acc10); acc11 = mfma16(L1, B1, acc11);
            acc00 = mfma16(A0, M0, acc00); acc01 = mfma16(A0, M1, acc01);
            acc10 = mfma16(A1, M0, acc10); acc11 = mfma16(A1, M1, acc11);
        }
        // half 1
        {
            s16x4 A0 = HALF(ah0, 1), A1 = HALF(ah1, 1), B0 = HALF(bh0, 1), B1 = HALF(bh1, 1);
            s16x4 L0 = HALF(al0, 1), L1 = HALF(al1, 1), M0 = HALF(bl0, 1), M1 = HALF(bl1, 1);
            acc00 = mfma16(A0, B0, acc00); acc01 = mfma16(A0, B1, acc01);
            acc10 = mfma16(A1, B0, acc10); acc11 = mfma16(A1, B1, acc11);
            acc00 = mfma16(L0, B0, acc00); acc01 = mfma16(L0, B1, acc01);
            acc10 = mfma16(L1, B0, acc10); acc11 = mfma16(L1, B1, acc11);
            acc00 = mfma16(A0, M0, acc00); acc01 = mfma16(A0, M1, acc01);
            acc10 = mfma16(A1, M0, acc10); acc11 = mfma16(A1, M1, acc11);
        }
    }

    // stage G tile to LDS (C/D layout: col = lane&15, row = 4*(lane>>4)+reg)
    __shared__ float Gt[64][68];
    #pragma unroll
    for (int r = 0; r < 4; ++r) {
        Gt[wm * 32 + 4 * q + r][wn * 32 + c]           = acc00[r];
        Gt[wm * 32 + 4 * q + r][wn * 32 + 16 + c]      = acc01[r];
        Gt[wm * 32 + 16 + 4 * q + r][wn * 32 + c]      = acc10[r];
        Gt[wm * 32 + 16 + 4 * q + r][wn * 32 + 16 + c] = acc11[r];
    }
    __syncthreads();

    if (n0 < 2048) {
        // ---- gate tile -> h_s ----
        u16* __restrict__ Hhn = Hhi + (size_t)(s & 1) * HN;
        u16* __restrict__ Hln = Hlo + (size_t)(s & 1) * HN;
        const int lu = t & 15, rg = t >> 4;
        const int u  = (n0 >> 2) + lu;
        const float* bb = Bias + (size_t)u * 12;
        const float B0_ = bb[0], c1r = bb[1], c2r = bb[2];
        const float B3_ = bb[3], c1z = bb[4], c2z = bb[5];
        const float B6_ = bb[6], c1n = bb[7], c2n = bb[8];
        const float B9_ = bb[9];
        #pragma unroll
        for (int rr = 0; rr < 4; ++rr) {
            const int ml = rg * 4 + rr;
            const int m  = m0 + ml;
            f32x4 gv = *(const f32x4*)&Gt[ml][4 * lu];
            const float lt = latv[m], ln = lonv[m];
            float r = sigm(gv.x + B0_ + lt * c1r + ln * c2r);
            float z = sigm(gv.y + B3_ + lt * c1z + ln * c2z);
            float n = tanh_f(fmaf(r, gv.w + B9_, gv.z + B6_ + lt * c1n + ln * c2n));
            float hold = bf2f(Hh[(size_t)m * HID + u]) + bf2f(Hl[(size_t)m * HID + u]);
            float h = n + z * (hold - n);
            u16 hi = f2bf(h);
            Hhn[(size_t)m * HID + u] = hi;
            Hln[(size_t)m * HID + u] = f2bf(h - bf2f(hi));
        }
    } else {
        // ---- proj tile -> out[s-1] ----
        const int cc = t & 63, r0 = t >> 6;
        const int o  = (n0 - 2048) + cc;
        const float bp = b_pr[o];
        float* obase = out + (size_t)(s - 1) * B_SZ * LAT + (size_t)m0 * LAT + o;
        #pragma unroll
        for (int i = 0; i < 16; ++i) {
            const int ml = i * 4 + r0;
            obase[(size_t)ml * LAT] = Gt[ml][cc] + bp;
        }
    }
}

extern "C" void kernel_launch(void* const* d_in, const int* in_sizes, int n_in,
                              void* d_out, int out_size, void* d_ws, size_t ws_size,
                              hipStream_t stream)
{
    const float* p0   = (const float*)d_in[0];
    const float* latv = (const float*)d_in[1];
    const float* lonv = (const float*)d_in[2];
    const float* W_ih = (const float*)d_in[3];
    const float* W_hh = (const float*)d_in[4];
    const float* b_ih = (const float*)d_in[5];
    const float* b_hh = (const float*)d_in[6];
    const float* W_pr = (const float*)d_in[7];
    const float* b_pr = (const float*)d_in[8];
    float* out = (float*)d_out;

    const int NS = out_size / (B_SZ * LAT) - 1;   // 100

    // workspace: gi1T region is reused for Whi/Wlo after k_h1 (stream-ordered).
    float* gi1T = (float*)d_ws;                       // 1536*2048 floats (12.58 MB)
    float* Bias = gi1T + 3 * HID * B_SZ;              // 512*12
    u16*   Hhi  = (u16*)(Bias + 512 * 12);            // 2*HN ushorts
    u16*   Hlo  = Hhi + 2 * HN;                       // 2*HN ushorts
    u16*   Whi  = (u16*)gi1T;                         // aliases gi1T (dead after k_h1)
    u16*   Wlo  = Whi + (size_t)NROW * HID;

    hipLaunchKernelGGL(k_bias, dim3(HID), dim3(64),  0, stream, W_ih, b_ih, b_hh, b_pr, Bias);
    hipLaunchKernelGGL(k_gi1,  dim3(256), dim3(512), 0, stream, p0, latv, lonv, W_ih, b_ih, gi1T, out);
    hipLaunchKernelGGL(k_h1,   dim3(4096), dim3(256), 0, stream, gi1T, Bias, Hhi, Hlo);
    hipLaunchKernelGGL(k_wsplit, dim3(NROW), dim3(512), 0, stream, W_ih, W_hh, W_pr, Whi, Wlo);

    for (int s = 2; s <= NS + 1; ++s) {
        const int ntc = (s <= NS) ? 36 : 4;
        const int ntb = (s <= NS) ? 0 : 32;
        hipLaunchKernelGGL(k_gemm, dim3(32 * ntc), dim3(256), 0, stream,
                           Hhi, Hlo, Whi, Wlo, Bias, b_pr, latv, lonv, out, s, NS, ntb, ntc);
    }
}

// Round 8
// 3037.021 us; speedup vs baseline: 4.6817x; 2.4656x over previous
//
#include <hip/hip_runtime.h>
#include <math.h>

// GRU rollout via MFMA 16x16x32 bf16, hi/lo split (3-pass ~ fp32).
// H and Wcat stored FRAGMENT-MAJOR: 1KB blocks of (16 rows x 32 k), element
// (n,k) at short-offset ((n>>4)*16 + (k>>5))*512 + ((k>>3)&3)*128 + (n&15)*8 + (k&7).
// A wave's MFMA operand load = one coalesced 1KB global_load_dwordx4 per frag.
// Per step: G[2048 x 2304] = h @ Wcat^T; gate tiles -> h_next (bf16 hi+lo),
// proj tiles -> out[s-1]. Step-1 handled via gi1 precompute (h0 = 0).

#define B_SZ 2048
#define LAT  256
#define HID  512
#define NROW 2304
#define HN   (B_SZ * HID)

typedef unsigned short u16;
typedef __attribute__((ext_vector_type(8))) short s16x8;
typedef __attribute__((ext_vector_type(4))) float f32x4;

__device__ __forceinline__ float sigm(float x) { return 1.0f / (1.0f + __expf(-x)); }
__device__ __forceinline__ float tanh_f(float x) {
    float e = __expf(-2.0f * fabsf(x));
    float t = (1.0f - e) / (1.0f + e);
    return copysignf(t, x);
}
__device__ __forceinline__ u16 f2bf(float x) {
    unsigned u = __float_as_uint(x);
    return (u16)((u + 0x7FFFu + ((u >> 16) & 1u)) >> 16);
}
__device__ __forceinline__ float bf2f(u16 h) { return __uint_as_float((unsigned)h << 16); }

// fragment-major short-offset for element (row n, k)
__device__ __forceinline__ size_t fidx(int n, int k) {
    return ((size_t)(n >> 4) * 16 + (k >> 5)) * 512 +
           (size_t)((k >> 3) & 3) * 128 + (n & 15) * 8 + (k & 7);
}

// ---------------- Bias[512][12] ----------------
__global__ __launch_bounds__(64) void k_bias(
    const float* __restrict__ W_ih, const float* __restrict__ b_ih,
    const float* __restrict__ b_hh, const float* __restrict__ b_pr,
    float* __restrict__ Bias)
{
    const int u = blockIdx.x;
    const int t = threadIdx.x;
    float dr = 0.f, dz = 0.f, dn = 0.f;
    for (int o = t; o < 256; o += 64) {
        float bo = b_pr[o];
        dr = fmaf(bo, W_ih[(size_t)u * 258 + o], dr);
        dz = fmaf(bo, W_ih[(size_t)(HID + u) * 258 + o], dz);
        dn = fmaf(bo, W_ih[(size_t)(2 * HID + u) * 258 + o], dn);
    }
    #pragma unroll
    for (int off = 32; off > 0; off >>= 1) {
        dr += __shfl_down(dr, off);
        dz += __shfl_down(dz, off);
        dn += __shfl_down(dn, off);
    }
    if (t == 0) {
        float* b = Bias + u * 12;
        b[0]  = b_ih[u] + b_hh[u] + dr;
        b[1]  = W_ih[(size_t)u * 258 + 256];
        b[2]  = W_ih[(size_t)u * 258 + 257];
        b[3]  = b_ih[HID + u] + b_hh[HID + u] + dz;
        b[4]  = W_ih[(size_t)(HID + u) * 258 + 256];
        b[5]  = W_ih[(size_t)(HID + u) * 258 + 257];
        b[6]  = b_ih[2 * HID + u] + dn;
        b[7]  = W_ih[(size_t)(2 * HID + u) * 258 + 256];
        b[8]  = W_ih[(size_t)(2 * HID + u) * 258 + 257];
        b[9]  = b_hh[2 * HID + u];
        b[10] = b_hh[u];
        b[11] = b_hh[HID + u];
    }
}

// ---------------- gi1_T[1536][2048] = x1 @ Wih^T + b_ih; out[0] = p0 ----------------
__global__ __launch_bounds__(512) void k_gi1(
    const float* __restrict__ p0, const float* __restrict__ latv,
    const float* __restrict__ lonv, const float* __restrict__ W_ih,
    const float* __restrict__ b_ih, float* __restrict__ gi1T,
    float* __restrict__ out)
{
    const int rb = blockIdx.x;
    const int t  = threadIdx.x;
    __shared__ float p0s[8][256];
    __shared__ float lat_s[8], lon_s[8];
    for (int i = t; i < 8 * 256; i += 512) {
        int r = i >> 8, o = i & 255;
        float v = p0[(size_t)(rb * 8 + r) * LAT + o];
        p0s[r][o] = v;
        out[(size_t)(rb * 8 + r) * LAT + o] = v;
    }
    if (t < 8) { lat_s[t] = latv[rb * 8 + t]; lon_s[t] = lonv[rb * 8 + t]; }
    __syncthreads();

    for (int gg = 0; gg < 3; ++gg) {
        const int grow = t + gg * 512;
        const float* wr = W_ih + (size_t)grow * 258;
        float acc[8];
        float bi = b_ih[grow];
        #pragma unroll
        for (int r = 0; r < 8; ++r) acc[r] = bi;
        for (int o = 0; o < 256; ++o) {
            float wv = wr[o];
            #pragma unroll
            for (int r = 0; r < 8; ++r) acc[r] = fmaf(wv, p0s[r][o], acc[r]);
        }
        float c1 = wr[256], c2 = wr[257];
        #pragma unroll
        for (int r = 0; r < 8; ++r) {
            acc[r] = fmaf(lat_s[r], c1, acc[r]);
            acc[r] = fmaf(lon_s[r], c2, acc[r]);
            gi1T[(size_t)grow * B_SZ + rb * 8 + r] = acc[r];
        }
    }
}

// ---------------- h_1 (h0 = 0), fragment-major bf16 hi/lo into buffer 1 ----------------
__global__ __launch_bounds__(256) void k_h1(
    const float* __restrict__ gi1T, const float* __restrict__ Bias,
    u16* __restrict__ Hhi, u16* __restrict__ Hlo)
{
    const int idx = blockIdx.x * 256 + threadIdx.x;
    const int row = idx & (B_SZ - 1);
    const int u   = idx >> 11;
    const float* bb = Bias + (size_t)u * 12;
    float r = sigm(gi1T[(size_t)u * B_SZ + row] + bb[10]);
    float z = sigm(gi1T[(size_t)(HID + u) * B_SZ + row] + bb[11]);
    float n = tanh_f(fmaf(r, bb[9], gi1T[(size_t)(2 * HID + u) * B_SZ + row]));
    float h = n - z * n;
    u16 hi = f2bf(h);
    size_t off = HN + fidx(row, u);
    Hhi[off] = hi;
    Hlo[off] = f2bf(h - bf2f(hi));
}

// ---------------- Wcat (2304 x 512) fused + split, fragment-major ----------------
__global__ __launch_bounds__(512) void k_wsplit(
    const float* __restrict__ W_ih, const float* __restrict__ W_hh,
    const float* __restrict__ W_pr, u16* __restrict__ Whi, u16* __restrict__ Wlo)
{
    const int n = blockIdx.x;
    const int k = threadIdx.x;
    const int u = n >> 2, g = n & 3;
    __shared__ float wr[256];
    if (n < 2048 && g != 3 && k < 256)
        wr[k] = W_ih[(size_t)(g * HID + u) * 258 + k];
    __syncthreads();

    float w;
    if (n >= 2048) {
        w = W_pr[(size_t)(n - 2048) * HID + k];
    } else if (g == 3) {
        w = W_hh[(size_t)(2 * HID + u) * HID + k];
    } else {
        float acc = 0.f;
        for (int o = 0; o < 256; ++o)
            acc = fmaf(wr[o], W_pr[(size_t)o * HID + k], acc);
        if (g == 0)      acc += W_hh[(size_t)u * HID + k];
        else if (g == 1) acc += W_hh[(size_t)(HID + u) * HID + k];
        w = acc;
    }
    u16 hi = f2bf(w);
    size_t off = fidx(n, k);
    Whi[off] = hi;
    Wlo[off] = f2bf(w - bf2f(hi));
}

// ---------------- main MFMA step: 128x128 tiles, 4 waves (2x2), K=512 ----------------
__global__ __launch_bounds__(256) void k_gemm(
    u16* __restrict__ Hhi, u16* __restrict__ Hlo,
    const u16* __restrict__ Whi, const u16* __restrict__ Wlo,
    const float* __restrict__ Bias, const float* __restrict__ b_pr,
    const float* __restrict__ latv, const float* __restrict__ lonv,
    float* __restrict__ out, int s, int ns, int ntb, int ntc)
{
    const int bid  = blockIdx.x;
    const int nt   = ntb + bid % ntc;
    const int mt   = bid / ntc;
    const int m0   = mt * 128, n0 = nt * 128;
    const int t    = threadIdx.x;
    const int lane = t & 63, wave = t >> 6;
    const int wm   = wave >> 1, wn = wave & 1;
    const int q    = lane >> 4, c = lane & 15;

    __shared__ float Gt[64][132];
    __shared__ float bias_s[32][12];
    if (n0 < 2048) {
        for (int i = t; i < 384; i += 256)          // FIX R7: 256-thread block
            ((float*)bias_s)[i] = Bias[(size_t)(n0 >> 2) * 12 + i];
    }

    const u16* __restrict__ Hh = Hhi + (size_t)((s - 1) & 1) * HN;
    const u16* __restrict__ Hl = Hlo + (size_t)((s - 1) & 1) * HN;

    // frag (block) offsets in shorts: block = xb*16 + kb, each 512 shorts
    int aoff[4], boff[4];
    #pragma unroll
    for (int i = 0; i < 4; ++i) {
        aoff[i] = ((mt * 8 + wm * 4 + i) * 16) * 512 + lane * 8;
        boff[i] = ((nt * 8 + wn * 4 + i) * 16) * 512 + lane * 8;
    }

    f32x4 acc[4][4];
    #pragma unroll
    for (int i = 0; i < 4; ++i)
        #pragma unroll
        for (int j = 0; j < 4; ++j) acc[i][j] = (f32x4){0.f, 0.f, 0.f, 0.f};

    #pragma unroll 2
    for (int kb = 0; kb < 16; ++kb) {
        const int ko = kb * 512;
        s16x8 ah[4], al[4], bh[4], bl[4];
        #pragma unroll
        for (int i = 0; i < 4; ++i) {
            ah[i] = *(const s16x8*)(Hh  + aoff[i] + ko);
            al[i] = *(const s16x8*)(Hl  + aoff[i] + ko);
            bh[i] = *(const s16x8*)(Whi + boff[i] + ko);
            bl[i] = *(const s16x8*)(Wlo + boff[i] + ko);
        }
        #pragma unroll
        for (int i = 0; i < 4; ++i)
            #pragma unroll
            for (int j = 0; j < 4; ++j) {
                acc[i][j] = __builtin_amdgcn_mfma_f32_16x16x32_bf16(ah[i], bh[j], acc[i][j], 0, 0, 0);
                acc[i][j] = __builtin_amdgcn_mfma_f32_16x16x32_bf16(al[i], bh[j], acc[i][j], 0, 0, 0);
                acc[i][j] = __builtin_amdgcn_mfma_f32_16x16x32_bf16(ah[i], bl[j], acc[i][j], 0, 0, 0);
            }
    }

    // ---- two-pass epilogue: stage 64 rows of G at a time ----
    u16* __restrict__ Hhn = Hhi + (size_t)(s & 1) * HN;
    u16* __restrict__ Hln = Hlo + (size_t)(s & 1) * HN;
    const int u0t = n0 >> 2;

    for (int half = 0; half < 2; ++half) {
        __syncthreads();    // Gt free (and bias_s visible on first pass)
        if (wm == half) {
            #pragma unroll
            for (int i = 0; i < 4; ++i)
                #pragma unroll
                for (int j = 0; j < 4; ++j)
                    #pragma unroll
                    for (int r = 0; r < 4; ++r)
                        Gt[i * 16 + 4 * q + r][wn * 64 + j * 16 + c] = acc[i][j][r];
        }
        __syncthreads();

        if (n0 < 2048) {
            // gates: 32 units, 64 rows this pass
            const int uo = t & 3;             // unit octet (8 units)
            const int ml = t >> 2;            // row-local 0..63
            const int m  = m0 + half * 64 + ml;
            const float lt = latv[m], ln = lonv[m];
            const size_t hoff = ((size_t)(m >> 4) * 16 + (u0t >> 5)) * 512 +
                                (size_t)uo * 128 + (m & 15) * 8;
            s16x8 hh8 = *(const s16x8*)(Hh + hoff);
            s16x8 hl8 = *(const s16x8*)(Hl + hoff);
            s16x8 vh, vl;
            #pragma unroll
            for (int j = 0; j < 8; ++j) {
                const float* bb = bias_s[uo * 8 + j];
                f32x4 gv = *(const f32x4*)&Gt[ml][(uo * 8 + j) * 4];
                float r = sigm(gv.x + bb[0] + lt * bb[1] + ln * bb[2]);
                float z = sigm(gv.y + bb[3] + lt * bb[4] + ln * bb[5]);
                float n = tanh_f(fmaf(r, gv.w + bb[9], gv.z + bb[6] + lt * bb[7] + ln * bb[8]));
                float hold = bf2f((u16)hh8[j]) + bf2f((u16)hl8[j]);
                float h = n + z * (hold - n);
                u16 hi = f2bf(h);
                vh[j] = (short)hi;
                vl[j] = (short)f2bf(h - bf2f(hi));
            }
            *(s16x8*)(Hhn + hoff) = vh;
            *(s16x8*)(Hln + hoff) = vl;
        } else {
            // projection: 128 latent cols, 64 rows this pass
            const int cl = t & 31, rg = t >> 5;     // 8 row-groups of 8
            const int o  = (n0 - 2048) + cl * 4;
            const float4 bp = *(const float4*)(b_pr + o);
            float* ob = out + (size_t)(s - 1) * B_SZ * LAT + o;
            #pragma unroll
            for (int i = 0; i < 8; ++i) {
                const int ml = rg * 8 + i;
                f32x4 g = *(const f32x4*)&Gt[ml][cl * 4];
                *(float4*)(ob + (size_t)(m0 + half * 64 + ml) * LAT) =
                    make_float4(g.x + bp.x, g.y + bp.y, g.z + bp.z, g.w + bp.w);
            }
        }
    }
}

extern "C" void kernel_launch(void* const* d_in, const int* in_sizes, int n_in,
                              void* d_out, int out_size, void* d_ws, size_t ws_size,
                              hipStream_t stream)
{
    const float* p0   = (const float*)d_in[0];
    const float* latv = (const float*)d_in[1];
    const float* lonv = (const float*)d_in[2];
    const float* W_ih = (const float*)d_in[3];
    const float* W_hh = (const float*)d_in[4];
    const float* b_ih = (const float*)d_in[5];
    const float* b_hh = (const float*)d_in[6];
    const float* W_pr = (const float*)d_in[7];
    const float* b_pr = (const float*)d_in[8];
    float* out = (float*)d_out;

    const int NS = out_size / (B_SZ * LAT) - 1;   // 100

    // workspace: Whi/Wlo alias gi1T (gi1T dead after k_h1; k_wsplit runs after)
    float* gi1T = (float*)d_ws;                       // 1536*2048 floats
    float* Bias = gi1T + 3 * HID * B_SZ;              // 512*12
    u16*   Hhi  = (u16*)(Bias + 512 * 12);            // 2*HN shorts
    u16*   Hlo  = Hhi + 2 * HN;                       // 2*HN shorts
    u16*   Whi  = (u16*)gi1T;                         // NROW*512 shorts
    u16*   Wlo  = Whi + (size_t)NROW * HID;           // NROW*512 shorts

    hipLaunchKernelGGL(k_bias,   dim3(HID),  dim3(64),  0, stream, W_ih, b_ih, b_hh, b_pr, Bias);
    hipLaunchKernelGGL(k_gi1,    dim3(256),  dim3(512), 0, stream, p0, latv, lonv, W_ih, b_ih, gi1T, out);
    hipLaunchKernelGGL(k_h1,     dim3(4096), dim3(256), 0, stream, gi1T, Bias, Hhi, Hlo);
    hipLaunchKernelGGL(k_wsplit, dim3(NROW), dim3(512), 0, stream, W_ih, W_hh, W_pr, Whi, Wlo);

    for (int s = 2; s <= NS + 1; ++s) {
        const int ntc = (s <= NS) ? 18 : 2;
        const int ntb = (s <= NS) ? 0 : 16;
        hipLaunchKernelGGL(k_gemm, dim3(16 * ntc), dim3(256), 0, stream,
                           Hhi, Hlo, Whi, Wlo, Bias, b_pr, latv, lonv, out, s, NS, ntb, ntc);
    }
}

// Round 9
// 2676.410 us; speedup vs baseline: 5.3125x; 1.1347x over previous
//
#include <hip/hip_runtime.h>
#include <math.h>

// GRU rollout via MFMA 16x16x32 bf16, hi/lo split (3-pass ~ fp32).
// Fragment-major operands (1KB = 16 rows x 32 k per block); coalesced 1KB loads.
// Fast path: per-step GATES-ONLY GEMM (2048x2048x512, 256 wgs = 1/CU, XCD-pinned
// N-panels), h_hi history -> one batched PROJ GEMM at the end (no feedback).
// Fallback (small ws): R8 fused per-step kernel.

#define B_SZ 2048
#define LAT  256
#define HID  512
#define NROW 2304
#define HN   (B_SZ * HID)

typedef unsigned short u16;
typedef __attribute__((ext_vector_type(8))) short s16x8;
typedef __attribute__((ext_vector_type(4))) float f32x4;

__device__ __forceinline__ float sigm(float x) { return 1.0f / (1.0f + __expf(-x)); }
__device__ __forceinline__ float tanh_f(float x) {
    float e = __expf(-2.0f * fabsf(x));
    float t = (1.0f - e) / (1.0f + e);
    return copysignf(t, x);
}
__device__ __forceinline__ u16 f2bf(float x) {
    unsigned u = __float_as_uint(x);
    return (u16)((u + 0x7FFFu + ((u >> 16) & 1u)) >> 16);
}
__device__ __forceinline__ float bf2f(u16 h) { return __uint_as_float((unsigned)h << 16); }

// fragment-major short-offset for element (row n, k)
__device__ __forceinline__ size_t fidx(int n, int k) {
    return ((size_t)(n >> 4) * 16 + (k >> 5)) * 512 +
           (size_t)((k >> 3) & 3) * 128 + (n & 15) * 8 + (k & 7);
}

// ---------------- Bias[512][12] ----------------
__global__ __launch_bounds__(64) void k_bias(
    const float* __restrict__ W_ih, const float* __restrict__ b_ih,
    const float* __restrict__ b_hh, const float* __restrict__ b_pr,
    float* __restrict__ Bias)
{
    const int u = blockIdx.x;
    const int t = threadIdx.x;
    float dr = 0.f, dz = 0.f, dn = 0.f;
    for (int o = t; o < 256; o += 64) {
        float bo = b_pr[o];
        dr = fmaf(bo, W_ih[(size_t)u * 258 + o], dr);
        dz = fmaf(bo, W_ih[(size_t)(HID + u) * 258 + o], dz);
        dn = fmaf(bo, W_ih[(size_t)(2 * HID + u) * 258 + o], dn);
    }
    #pragma unroll
    for (int off = 32; off > 0; off >>= 1) {
        dr += __shfl_down(dr, off);
        dz += __shfl_down(dz, off);
        dn += __shfl_down(dn, off);
    }
    if (t == 0) {
        float* b = Bias + u * 12;
        b[0]  = b_ih[u] + b_hh[u] + dr;
        b[1]  = W_ih[(size_t)u * 258 + 256];
        b[2]  = W_ih[(size_t)u * 258 + 257];
        b[3]  = b_ih[HID + u] + b_hh[HID + u] + dz;
        b[4]  = W_ih[(size_t)(HID + u) * 258 + 256];
        b[5]  = W_ih[(size_t)(HID + u) * 258 + 257];
        b[6]  = b_ih[2 * HID + u] + dn;
        b[7]  = W_ih[(size_t)(2 * HID + u) * 258 + 256];
        b[8]  = W_ih[(size_t)(2 * HID + u) * 258 + 257];
        b[9]  = b_hh[2 * HID + u];
        b[10] = b_hh[u];
        b[11] = b_hh[HID + u];
    }
}

// ---------------- gi1_T[1536][2048] = x1 @ Wih^T + b_ih; out[0] = p0 ----------------
__global__ __launch_bounds__(512) void k_gi1(
    const float* __restrict__ p0, const float* __restrict__ latv,
    const float* __restrict__ lonv, const float* __restrict__ W_ih,
    const float* __restrict__ b_ih, float* __restrict__ gi1T,
    float* __restrict__ out)
{
    const int rb = blockIdx.x;
    const int t  = threadIdx.x;
    __shared__ float p0s[8][256];
    __shared__ float lat_s[8], lon_s[8];
    for (int i = t; i < 8 * 256; i += 512) {
        int r = i >> 8, o = i & 255;
        float v = p0[(size_t)(rb * 8 + r) * LAT + o];
        p0s[r][o] = v;
        out[(size_t)(rb * 8 + r) * LAT + o] = v;
    }
    if (t < 8) { lat_s[t] = latv[rb * 8 + t]; lon_s[t] = lonv[rb * 8 + t]; }
    __syncthreads();

    for (int gg = 0; gg < 3; ++gg) {
        const int grow = t + gg * 512;
        const float* wr = W_ih + (size_t)grow * 258;
        float acc[8];
        float bi = b_ih[grow];
        #pragma unroll
        for (int r = 0; r < 8; ++r) acc[r] = bi;
        for (int o = 0; o < 256; ++o) {
            float wv = wr[o];
            #pragma unroll
            for (int r = 0; r < 8; ++r) acc[r] = fmaf(wv, p0s[r][o], acc[r]);
        }
        float c1 = wr[256], c2 = wr[257];
        #pragma unroll
        for (int r = 0; r < 8; ++r) {
            acc[r] = fmaf(lat_s[r], c1, acc[r]);
            acc[r] = fmaf(lon_s[r], c2, acc[r]);
            gi1T[(size_t)grow * B_SZ + rb * 8 + r] = acc[r];
        }
    }
}

// ---------------- h_1 (h0 = 0) -> slab 1 of Hhi and Hlo ----------------
__global__ __launch_bounds__(256) void k_h1(
    const float* __restrict__ gi1T, const float* __restrict__ Bias,
    u16* __restrict__ Hhi, u16* __restrict__ Hlo)
{
    const int idx = blockIdx.x * 256 + threadIdx.x;
    const int row = idx & (B_SZ - 1);
    const int u   = idx >> 11;
    const float* bb = Bias + (size_t)u * 12;
    float r = sigm(gi1T[(size_t)u * B_SZ + row] + bb[10]);
    float z = sigm(gi1T[(size_t)(HID + u) * B_SZ + row] + bb[11]);
    float n = tanh_f(fmaf(r, bb[9], gi1T[(size_t)(2 * HID + u) * B_SZ + row]));
    float h = n - z * n;
    u16 hi = f2bf(h);
    size_t off = HN + fidx(row, u);
    Hhi[off] = hi;
    Hlo[off] = f2bf(h - bf2f(hi));
}

// ---------------- Wcat (2304 x 512) fused + split, fragment-major ----------------
__global__ __launch_bounds__(512) void k_wsplit(
    const float* __restrict__ W_ih, const float* __restrict__ W_hh,
    const float* __restrict__ W_pr, u16* __restrict__ Whi, u16* __restrict__ Wlo)
{
    const int n = blockIdx.x;
    const int k = threadIdx.x;
    const int u = n >> 2, g = n & 3;
    __shared__ float wr[256];
    if (n < 2048 && g != 3 && k < 256)
        wr[k] = W_ih[(size_t)(g * HID + u) * 258 + k];
    __syncthreads();

    float w;
    if (n >= 2048) {
        w = W_pr[(size_t)(n - 2048) * HID + k];
    } else if (g == 3) {
        w = W_hh[(size_t)(2 * HID + u) * HID + k];
    } else {
        float acc = 0.f;
        for (int o = 0; o < 256; ++o)
            acc = fmaf(wr[o], W_pr[(size_t)o * HID + k], acc);
        if (g == 0)      acc += W_hh[(size_t)u * HID + k];
        else if (g == 1) acc += W_hh[(size_t)(HID + u) * HID + k];
        w = acc;
    }
    u16 hi = f2bf(w);
    size_t off = fidx(n, k);
    Whi[off] = hi;
    Wlo[off] = f2bf(w - bf2f(hi));
}

// ---------------- FAST PATH: gates-only step GEMM (2048x2048x512) ----------------
// 256 wgs = 1/CU. XCD-pinned N-panels: xcd = bid&7 owns nt {2x, 2x+1}.
// Reads Hhi slab sA (+ Hlo ring ra), writes Hhi slab sW (+ Hlo ring rw).
__global__ __launch_bounds__(256) void k_gates(
    u16* __restrict__ Hhi, u16* __restrict__ Hlo,
    const u16* __restrict__ Whi, const u16* __restrict__ Wlo,
    const float* __restrict__ Bias,
    const float* __restrict__ latv, const float* __restrict__ lonv,
    int sA, int sW, int ra, int rw)
{
    const int bid = blockIdx.x;
    const int p   = (bid & 7) * 32 + (bid >> 3);
    const int nt  = p >> 4, mt = p & 15;
    const int m0  = mt * 128, n0 = nt * 128;
    const int t    = threadIdx.x;
    const int lane = t & 63, wave = t >> 6;
    const int wm   = wave >> 1, wn = wave & 1;
    const int q    = lane >> 4, c = lane & 15;

    __shared__ float Gt[64][132];
    __shared__ float bias_s[32][12];
    for (int i = t; i < 384; i += 256)
        ((float*)bias_s)[i] = Bias[(size_t)(n0 >> 2) * 12 + i];

    const u16* __restrict__ Hh = Hhi + (size_t)sA * HN;
    const u16* __restrict__ Hl = Hlo + (size_t)ra * HN;

    int aoff[4], boff[4];
    #pragma unroll
    for (int i = 0; i < 4; ++i) {
        aoff[i] = ((mt * 8 + wm * 4 + i) * 16) * 512 + lane * 8;
        boff[i] = ((nt * 8 + wn * 4 + i) * 16) * 512 + lane * 8;
    }

    f32x4 acc[4][4];
    #pragma unroll
    for (int i = 0; i < 4; ++i)
        #pragma unroll
        for (int j = 0; j < 4; ++j) acc[i][j] = (f32x4){0.f, 0.f, 0.f, 0.f};

    #pragma unroll 2
    for (int kb = 0; kb < 16; ++kb) {
        const int ko = kb * 512;
        s16x8 ah[4], al[4], bh[4], bl[4];
        #pragma unroll
        for (int i = 0; i < 4; ++i) {
            ah[i] = *(const s16x8*)(Hh  + aoff[i] + ko);
            al[i] = *(const s16x8*)(Hl  + aoff[i] + ko);
            bh[i] = *(const s16x8*)(Whi + boff[i] + ko);
            bl[i] = *(const s16x8*)(Wlo + boff[i] + ko);
        }
        #pragma unroll
        for (int i = 0; i < 4; ++i)
            #pragma unroll
            for (int j = 0; j < 4; ++j) {
                acc[i][j] = __builtin_amdgcn_mfma_f32_16x16x32_bf16(ah[i], bh[j], acc[i][j], 0, 0, 0);
                acc[i][j] = __builtin_amdgcn_mfma_f32_16x16x32_bf16(al[i], bh[j], acc[i][j], 0, 0, 0);
                acc[i][j] = __builtin_amdgcn_mfma_f32_16x16x32_bf16(ah[i], bl[j], acc[i][j], 0, 0, 0);
            }
    }

    u16* __restrict__ Hhn = Hhi + (size_t)sW * HN;
    u16* __restrict__ Hln = Hlo + (size_t)rw * HN;

    for (int half = 0; half < 2; ++half) {
        __syncthreads();
        if (wm == half) {
            #pragma unroll
            for (int i = 0; i < 4; ++i)
                #pragma unroll
                for (int j = 0; j < 4; ++j)
                    #pragma unroll
                    for (int r = 0; r < 4; ++r)
                        Gt[i * 16 + 4 * q + r][wn * 64 + j * 16 + c] = acc[i][j][r];
        }
        __syncthreads();

        const int uo = t & 3;
        const int ml = t >> 2;
        const int m  = m0 + half * 64 + ml;
        const float lt = latv[m], ln = lonv[m];
        const size_t hoff = ((size_t)(m >> 4) * 16 + nt) * 512 +
                            (size_t)uo * 128 + (m & 15) * 8;
        s16x8 hh8 = *(const s16x8*)(Hh + hoff);
        s16x8 hl8 = *(const s16x8*)(Hl + hoff);
        s16x8 vh, vl;
        #pragma unroll
        for (int j = 0; j < 8; ++j) {
            const float* bb = bias_s[uo * 8 + j];
            f32x4 gv = *(const f32x4*)&Gt[ml][(uo * 8 + j) * 4];
            float r = sigm(gv.x + bb[0] + lt * bb[1] + ln * bb[2]);
            float z = sigm(gv.y + bb[3] + lt * bb[4] + ln * bb[5]);
            float n = tanh_f(fmaf(r, gv.w + bb[9], gv.z + bb[6] + lt * bb[7] + ln * bb[8]));
            float hold = bf2f((u16)hh8[j]) + bf2f((u16)hl8[j]);
            float h = n + z * (hold - n);
            u16 hi = f2bf(h);
            vh[j] = (short)hi;
            vl[j] = (short)f2bf(h - bf2f(hi));
        }
        *(s16x8*)(Hhn + hoff) = vh;
        *(s16x8*)(Hln + hoff) = vl;
    }
}

// ---------------- FAST PATH: batched projection over all steps ----------------
// grid = NS*32: bid>>1 -> (slab, mt), bid&1 -> N half. 2-pass: Ahi*(Bhi+Blo).
__global__ __launch_bounds__(256) void k_proj(
    const u16* __restrict__ Hhi, const u16* __restrict__ Whi,
    const u16* __restrict__ Wlo, const float* __restrict__ b_pr,
    float* __restrict__ out)
{
    const int bid  = blockIdx.x;
    const int pt   = bid >> 1, ntp = bid & 1;
    const int slab = (pt >> 4) + 1;
    const int mt   = pt & 15;
    const int m0   = mt * 128;
    const int t    = threadIdx.x;
    const int lane = t & 63, wave = t >> 6;
    const int wm   = wave >> 1, wn = wave & 1;
    const int q    = lane >> 4, c = lane & 15;

    __shared__ float Gt[64][132];

    const u16* __restrict__ Hh = Hhi + (size_t)slab * HN;

    int aoff[4], boff[4];
    #pragma unroll
    for (int i = 0; i < 4; ++i) {
        aoff[i] = ((mt * 8 + wm * 4 + i) * 16) * 512 + lane * 8;
        boff[i] = ((128 + ntp * 8 + wn * 4 + i) * 16) * 512 + lane * 8;
    }

    f32x4 acc[4][4];
    #pragma unroll
    for (int i = 0; i < 4; ++i)
        #pragma unroll
        for (int j = 0; j < 4; ++j) acc[i][j] = (f32x4){0.f, 0.f, 0.f, 0.f};

    #pragma unroll 2
    for (int kb = 0; kb < 16; ++kb) {
        const int ko = kb * 512;
        s16x8 ah[4], bh[4], bl[4];
        #pragma unroll
        for (int i = 0; i < 4; ++i) {
            ah[i] = *(const s16x8*)(Hh  + aoff[i] + ko);
            bh[i] = *(const s16x8*)(Whi + boff[i] + ko);
            bl[i] = *(const s16x8*)(Wlo + boff[i] + ko);
        }
        #pragma unroll
        for (int i = 0; i < 4; ++i)
            #pragma unroll
            for (int j = 0; j < 4; ++j) {
                acc[i][j] = __builtin_amdgcn_mfma_f32_16x16x32_bf16(ah[i], bh[j], acc[i][j], 0, 0, 0);
                acc[i][j] = __builtin_amdgcn_mfma_f32_16x16x32_bf16(ah[i], bl[j], acc[i][j], 0, 0, 0);
            }
    }

    for (int half = 0; half < 2; ++half) {
        __syncthreads();
        if (wm == half) {
            #pragma unroll
            for (int i = 0; i < 4; ++i)
                #pragma unroll
                for (int j = 0; j < 4; ++j)
                    #pragma unroll
                    for (int r = 0; r < 4; ++r)
                        Gt[i * 16 + 4 * q + r][wn * 64 + j * 16 + c] = acc[i][j][r];
        }
        __syncthreads();

        const int cl = t & 31, rg = t >> 5;
        const int o  = ntp * 128 + cl * 4;
        const float4 bp = *(const float4*)(b_pr + o);
        float* ob = out + (size_t)slab * B_SZ * LAT + o;
        #pragma unroll
        for (int i = 0; i < 8; ++i) {
            const int ml = rg * 8 + i;
            f32x4 g = *(const f32x4*)&Gt[ml][cl * 4];
            *(float4*)(ob + (size_t)(m0 + half * 64 + ml) * LAT) =
                make_float4(g.x + bp.x, g.y + bp.y, g.z + bp.z, g.w + bp.w);
        }
    }
}

// ---------------- FALLBACK (R8): fused per-step 128x128 GEMM ----------------
__global__ __launch_bounds__(256) void k_gemm(
    u16* __restrict__ Hhi, u16* __restrict__ Hlo,
    const u16* __restrict__ Whi, const u16* __restrict__ Wlo,
    const float* __restrict__ Bias, const float* __restrict__ b_pr,
    const float* __restrict__ latv, const float* __restrict__ lonv,
    float* __restrict__ out, int s, int ns, int ntb, int ntc)
{
    const int bid  = blockIdx.x;
    const int nt   = ntb + bid % ntc;
    const int mt   = bid / ntc;
    const int m0   = mt * 128, n0 = nt * 128;
    const int t    = threadIdx.x;
    const int lane = t & 63, wave = t >> 6;
    const int wm   = wave >> 1, wn = wave & 1;
    const int q    = lane >> 4, c = lane & 15;

    __shared__ float Gt[64][132];
    __shared__ float bias_s[32][12];
    if (n0 < 2048) {
        for (int i = t; i < 384; i += 256)
            ((float*)bias_s)[i] = Bias[(size_t)(n0 >> 2) * 12 + i];
    }

    const u16* __restrict__ Hh = Hhi + (size_t)((s - 1) & 1) * HN;
    const u16* __restrict__ Hl = Hlo + (size_t)((s - 1) & 1) * HN;

    int aoff[4], boff[4];
    #pragma unroll
    for (int i = 0; i < 4; ++i) {
        aoff[i] = ((mt * 8 + wm * 4 + i) * 16) * 512 + lane * 8;
        boff[i] = ((nt * 8 + wn * 4 + i) * 16) * 512 + lane * 8;
    }

    f32x4 acc[4][4];
    #pragma unroll
    for (int i = 0; i < 4; ++i)
        #pragma unroll
        for (int j = 0; j < 4; ++j) acc[i][j] = (f32x4){0.f, 0.f, 0.f, 0.f};

    #pragma unroll 2
    for (int kb = 0; kb < 16; ++kb) {
        const int ko = kb * 512;
        s16x8 ah[4], al[4], bh[4], bl[4];
        #pragma unroll
        for (int i = 0; i < 4; ++i) {
            ah[i] = *(const s16x8*)(Hh  + aoff[i] + ko);
            al[i] = *(const s16x8*)(Hl  + aoff[i] + ko);
            bh[i] = *(const s16x8*)(Whi + boff[i] + ko);
            bl[i] = *(const s16x8*)(Wlo + boff[i] + ko);
        }
        #pragma unroll
        for (int i = 0; i < 4; ++i)
            #pragma unroll
            for (int j = 0; j < 4; ++j) {
                acc[i][j] = __builtin_amdgcn_mfma_f32_16x16x32_bf16(ah[i], bh[j], acc[i][j], 0, 0, 0);
                acc[i][j] = __builtin_amdgcn_mfma_f32_16x16x32_bf16(al[i], bh[j], acc[i][j], 0, 0, 0);
                acc[i][j] = __builtin_amdgcn_mfma_f32_16x16x32_bf16(ah[i], bl[j], acc[i][j], 0, 0, 0);
            }
    }

    u16* __restrict__ Hhn = Hhi + (size_t)(s & 1) * HN;
    u16* __restrict__ Hln = Hlo + (size_t)(s & 1) * HN;
    const int u0t = n0 >> 2;

    for (int half = 0; half < 2; ++half) {
        __syncthreads();
        if (wm == half) {
            #pragma unroll
            for (int i = 0; i < 4; ++i)
                #pragma unroll
                for (int j = 0; j < 4; ++j)
                    #pragma unroll
                    for (int r = 0; r < 4; ++r)
                        Gt[i * 16 + 4 * q + r][wn * 64 + j * 16 + c] = acc[i][j][r];
        }
        __syncthreads();

        if (n0 < 2048) {
            const int uo = t & 3;
            const int ml = t >> 2;
            const int m  = m0 + half * 64 + ml;
            const float lt = latv[m], ln = lonv[m];
            const size_t hoff = ((size_t)(m >> 4) * 16 + (u0t >> 5)) * 512 +
                                (size_t)uo * 128 + (m & 15) * 8;
            s16x8 hh8 = *(const s16x8*)(Hh + hoff);
            s16x8 hl8 = *(const s16x8*)(Hl + hoff);
            s16x8 vh, vl;
            #pragma unroll
            for (int j = 0; j < 8; ++j) {
                const float* bb = bias_s[uo * 8 + j];
                f32x4 gv = *(const f32x4*)&Gt[ml][(uo * 8 + j) * 4];
                float r = sigm(gv.x + bb[0] + lt * bb[1] + ln * bb[2]);
                float z = sigm(gv.y + bb[3] + lt * bb[4] + ln * bb[5]);
                float n = tanh_f(fmaf(r, gv.w + bb[9], gv.z + bb[6] + lt * bb[7] + ln * bb[8]));
                float hold = bf2f((u16)hh8[j]) + bf2f((u16)hl8[j]);
                float h = n + z * (hold - n);
                u16 hi = f2bf(h);
                vh[j] = (short)hi;
                vl[j] = (short)f2bf(h - bf2f(hi));
            }
            *(s16x8*)(Hhn + hoff) = vh;
            *(s16x8*)(Hln + hoff) = vl;
        } else {
            const int cl = t & 31, rg = t >> 5;
            const int o  = (n0 - 2048) + cl * 4;
            const float4 bp = *(const float4*)(b_pr + o);
            float* ob = out + (size_t)(s - 1) * B_SZ * LAT + o;
            #pragma unroll
            for (int i = 0; i < 8; ++i) {
                const int ml = rg * 8 + i;
                f32x4 g = *(const f32x4*)&Gt[ml][cl * 4];
                *(float4*)(ob + (size_t)(m0 + half * 64 + ml) * LAT) =
                    make_float4(g.x + bp.x, g.y + bp.y, g.z + bp.z, g.w + bp.w);
            }
        }
    }
}

extern "C" void kernel_launch(void* const* d_in, const int* in_sizes, int n_in,
                              void* d_out, int out_size, void* d_ws, size_t ws_size,
                              hipStream_t stream)
{
    const float* p0   = (const float*)d_in[0];
    const float* latv = (const float*)d_in[1];
    const float* lonv = (const float*)d_in[2];
    const float* W_ih = (const float*)d_in[3];
    const float* W_hh = (const float*)d_in[4];
    const float* b_ih = (const float*)d_in[5];
    const float* b_hh = (const float*)d_in[6];
    const float* W_pr = (const float*)d_in[7];
    const float* b_pr = (const float*)d_in[8];
    float* out = (float*)d_out;

    const int NS = out_size / (B_SZ * LAT) - 1;   // 100

    // layout: gi1T | Bias | Hhi[nslab] | Hlo[2]; Whi/Wlo alias gi1T (dead after k_h1)
    float* gi1T = (float*)d_ws;
    float* Bias = gi1T + 3 * HID * B_SZ;
    u16*   Whi  = (u16*)gi1T;
    u16*   Wlo  = Whi + (size_t)NROW * HID;

    const size_t offH     = ((size_t)3 * HID * B_SZ + 512 * 12) * sizeof(float);
    const size_t slabB    = (size_t)HN * sizeof(u16);
    const size_t needFast = offH + (size_t)(NS + 1) * slabB + 2 * slabB;
    const bool   fast     = ws_size >= needFast;
    const int    nslabHi  = fast ? (NS + 1) : 2;

    u16* Hhi = (u16*)((char*)d_ws + offH);
    u16* Hlo = Hhi + (size_t)nslabHi * HN;

    hipLaunchKernelGGL(k_bias,   dim3(HID),  dim3(64),  0, stream, W_ih, b_ih, b_hh, b_pr, Bias);
    hipLaunchKernelGGL(k_gi1,    dim3(256),  dim3(512), 0, stream, p0, latv, lonv, W_ih, b_ih, gi1T, out);
    hipLaunchKernelGGL(k_h1,     dim3(4096), dim3(256), 0, stream, gi1T, Bias, Hhi, Hlo);
    hipLaunchKernelGGL(k_wsplit, dim3(NROW), dim3(512), 0, stream, W_ih, W_hh, W_pr, Whi, Wlo);

    if (fast) {
        for (int s = 2; s <= NS; ++s) {
            hipLaunchKernelGGL(k_gates, dim3(256), dim3(256), 0, stream,
                               Hhi, Hlo, Whi, Wlo, Bias, latv, lonv,
                               s - 1, s, (s - 1) & 1, s & 1);
        }
        hipLaunchKernelGGL(k_proj, dim3(NS * 32), dim3(256), 0, stream,
                           Hhi, Whi, Wlo, b_pr, out);
    } else {
        for (int s = 2; s <= NS + 1; ++s) {
            const int ntc = (s <= NS) ? 18 : 2;
            const int ntb = (s <= NS) ? 0 : 16;
            hipLaunchKernelGGL(k_gemm, dim3(16 * ntc), dim3(256), 0, stream,
                               Hhi, Hlo, Whi, Wlo, Bias, b_pr, latv, lonv, out, s, NS, ntb, ntc);
        }
    }
}